// Round 1
// baseline (911.695 us; speedup 1.0000x reference)
//
#include <hip/hip_runtime.h>
#include <cstdint>
#include <cstddef>

#define NN 100000
#define NE 1600000
#define D  128

// ---------------------------------------------------------------- CSR build
__global__ __launch_bounds__(256) void k_count(const int* __restrict__ dstv,
                                               int* __restrict__ cnt, int e) {
    int i = blockIdx.x * 256 + threadIdx.x;
    if (i < e) atomicAdd(&cnt[dstv[i]], 1);
}

__global__ __launch_bounds__(256) void k_dinv(const int* __restrict__ cnt,
                                              float* __restrict__ dinv, int n) {
    int i = blockIdx.x * 256 + threadIdx.x;
    if (i < n) dinv[i] = rsqrtf((float)cnt[i] + 1.0f);
}

// chunk = 1024 elements per block (256 threads x 4)
__global__ __launch_bounds__(256) void k_scan1(const int* __restrict__ cnt,
                                               int* __restrict__ rowptr,
                                               int* __restrict__ bsum, int n) {
    __shared__ int s[256];
    int tid = threadIdx.x;
    int base = blockIdx.x * 1024 + tid * 4;
    int v[4]; int sum = 0;
#pragma unroll
    for (int j = 0; j < 4; ++j) { int idx = base + j; v[j] = (idx < n) ? cnt[idx] : 0; sum += v[j]; }
    s[tid] = sum;
    __syncthreads();
    for (int off = 1; off < 256; off <<= 1) {
        int t = (tid >= off) ? s[tid - off] : 0;
        __syncthreads();
        s[tid] += t;
        __syncthreads();
    }
    if (tid == 255) bsum[blockIdx.x] = s[255];
    int run = (tid > 0) ? s[tid - 1] : 0;
#pragma unroll
    for (int j = 0; j < 4; ++j) { int idx = base + j; if (idx < n) rowptr[idx] = run; run += v[j]; }
}

__global__ void k_scan2(const int* __restrict__ bsum, int* __restrict__ boff, int nb) {
    if (threadIdx.x == 0 && blockIdx.x == 0) {
        int run = 0;
        for (int i = 0; i < nb; ++i) { int t = bsum[i]; boff[i] = run; run += t; }
    }
}

__global__ __launch_bounds__(256) void k_add(int* __restrict__ rowptr,
                                             const int* __restrict__ boff,
                                             int* __restrict__ cursor, int n, int e) {
    int i = blockIdx.x * 256 + threadIdx.x;
    if (i < n) { int v = rowptr[i] + boff[i >> 10]; rowptr[i] = v; cursor[i] = v; }
    if (i == 0) rowptr[n] = e;
}

__global__ __launch_bounds__(256) void k_fill(const int* __restrict__ srcv,
                                              const int* __restrict__ dstv,
                                              int* __restrict__ cursor,
                                              int* __restrict__ col, int e) {
    int i = blockIdx.x * 256 + threadIdx.x;
    if (i < e) { int d = dstv[i]; int p = atomicAdd(&cursor[d], 1); col[p] = srcv[i]; }
}

// ---------------------------------------------------------------- GEMM  Y = X @ W
// 32 rows x 128 cols per block, full W staged in LDS, 4x4 register blocking.
__global__ __launch_bounds__(256) void k_gemm(const float* __restrict__ X,
                                              const float* __restrict__ W,
                                              float* __restrict__ Y) {
    __shared__ float4 sW[128 * 32];  // W[128][128]
    __shared__ float4 sX[32 * 32];   // X tile [32][128]
    int tid  = threadIdx.x;
    int row0 = blockIdx.x * 32;

    const float4* W4 = (const float4*)W;
    for (int i = tid; i < 4096; i += 256) sW[i] = W4[i];
    const float4* X4 = (const float4*)(X + (size_t)row0 * D);
    for (int i = tid; i < 1024; i += 256) sX[i] = X4[i];
    __syncthreads();

    int tx = tid & 31;   // col group of 4
    int ty = tid >> 5;   // row group of 4
    float acc[4][4] = {};

#pragma unroll 4
    for (int k = 0; k < 128; k += 4) {
        float4 b0 = sW[(k + 0) * 32 + tx];
        float4 b1 = sW[(k + 1) * 32 + tx];
        float4 b2 = sW[(k + 2) * 32 + tx];
        float4 b3 = sW[(k + 3) * 32 + tx];
#pragma unroll
        for (int i = 0; i < 4; ++i) {
            float4 a = sX[(ty * 4 + i) * 32 + (k >> 2)];
            acc[i][0] = fmaf(a.x, b0.x, fmaf(a.y, b1.x, fmaf(a.z, b2.x, fmaf(a.w, b3.x, acc[i][0]))));
            acc[i][1] = fmaf(a.x, b0.y, fmaf(a.y, b1.y, fmaf(a.z, b2.y, fmaf(a.w, b3.y, acc[i][1]))));
            acc[i][2] = fmaf(a.x, b0.z, fmaf(a.y, b1.z, fmaf(a.z, b2.z, fmaf(a.w, b3.z, acc[i][2]))));
            acc[i][3] = fmaf(a.x, b0.w, fmaf(a.y, b1.w, fmaf(a.z, b2.w, fmaf(a.w, b3.w, acc[i][3]))));
        }
    }

#pragma unroll
    for (int i = 0; i < 4; ++i) {
        int r = row0 + ty * 4 + i;
        float4 o = make_float4(acc[i][0], acc[i][1], acc[i][2], acc[i][3]);
        *(float4*)&Y[(size_t)r * D + tx * 4] = o;
    }
}

// ---------------------------------------------------------------- aggregation
// one 64-lane wave per destination node, 2 floats per lane.
// out[v] = relu?( dinv[v]*(sum_{u->v} dinv[u]*h[u] + dinv[v]*h[v]) + b )
// if normalize: row-L2-normalize instead of relu.
__global__ __launch_bounds__(256) void k_agg(const float* __restrict__ H,
                                             const int* __restrict__ rowptr,
                                             const int* __restrict__ col,
                                             const float* __restrict__ dinv,
                                             const float* __restrict__ bias,
                                             float* __restrict__ out,
                                             int n, int relu, int normalize) {
    int node = blockIdx.x * 4 + (threadIdx.x >> 6);
    int lane = threadIdx.x & 63;
    if (node >= n) return;

    const float2* H2 = (const float2*)H;
    float di  = dinv[node];
    int beg = rowptr[node];
    int end = rowptr[node + 1];

    float ax = 0.0f, ay = 0.0f;
    for (int e = beg; e < end; ++e) {
        int s = col[e];
        float w = dinv[s];
        float2 v = H2[(size_t)s * 64 + lane];
        ax = fmaf(w, v.x, ax);
        ay = fmaf(w, v.y, ay);
    }
    float2 hv = H2[(size_t)node * 64 + lane];
    ax = fmaf(di, hv.x, ax);   // + dinv[v]*h[v]
    ay = fmaf(di, hv.y, ay);
    float2 bv = ((const float2*)bias)[lane];
    float ox = fmaf(di, ax, bv.x);
    float oy = fmaf(di, ay, bv.y);

    if (relu) {
        ox = fmaxf(ox, 0.0f);
        oy = fmaxf(oy, 0.0f);
    }
    if (normalize) {
        float ss = ox * ox + oy * oy;
#pragma unroll
        for (int off = 32; off > 0; off >>= 1) ss += __shfl_xor(ss, off, 64);
        float nrm = fmaxf(sqrtf(ss), 1e-12f);
        float inv = 1.0f / nrm;
        ox *= inv; oy *= inv;
    }
    float2* O2 = (float2*)out;
    float2 o; o.x = ox; o.y = oy;
    O2[(size_t)node * 64 + lane] = o;
}

// ---------------------------------------------------------------- launch
extern "C" void kernel_launch(void* const* d_in, const int* in_sizes, int n_in,
                              void* d_out, int out_size, void* d_ws, size_t ws_size,
                              hipStream_t stream) {
    const float* x  = (const float*)d_in[0];
    const int*   ei = (const int*)d_in[1];
    const float* W1 = (const float*)d_in[2];
    const float* b1 = (const float*)d_in[3];
    const float* W2 = (const float*)d_in[4];
    const float* b2 = (const float*)d_in[5];
    const float* W3 = (const float*)d_in[6];
    const float* b3 = (const float*)d_in[7];
    float* out = (float*)d_out;

    const int* srcv = ei;
    const int* dstv = ei + NE;

    // workspace carve
    char* w = (char*)d_ws;
    float* hA    = (float*)w; w += (size_t)NN * D * sizeof(float);   // 51.2 MB
    int*   degc  = (int*)w;   w += (size_t)NN * sizeof(int);
    float* dinv  = (float*)w; w += (size_t)NN * sizeof(float);
    int*   rowp  = (int*)w;   w += (size_t)(NN + 1) * sizeof(int);
    int*   curs  = (int*)w;   w += (size_t)NN * sizeof(int);
    int*   bsum  = (int*)w;   w += 128 * sizeof(int);
    int*   boff  = (int*)w;   w += 128 * sizeof(int);
    int*   col   = (int*)w;   w += (size_t)NE * sizeof(int);

    const int nb = (NN + 1023) / 1024;  // 98

    hipMemsetAsync(degc, 0, (size_t)NN * sizeof(int), stream);
    k_count<<<(NE + 255) / 256, 256, 0, stream>>>(dstv, degc, NE);
    k_dinv <<<(NN + 255) / 256, 256, 0, stream>>>(degc, dinv, NN);
    k_scan1<<<nb, 256, 0, stream>>>(degc, rowp, bsum, NN);
    k_scan2<<<1, 64, 0, stream>>>(bsum, boff, nb);
    k_add  <<<(NN + 255) / 256, 256, 0, stream>>>(rowp, boff, curs, NN, NE);
    k_fill <<<(NE + 255) / 256, 256, 0, stream>>>(srcv, dstv, curs, col, NE);

    dim3 gGemm(NN / 32);      // 100000 / 32 = 3125 exactly
    dim3 gAgg((NN + 3) / 4);  // 4 nodes per 256-thread block

    // layer 1
    k_gemm<<<gGemm, 256, 0, stream>>>(x, W1, hA);
    k_agg <<<gAgg, 256, 0, stream>>>(hA, rowp, col, dinv, b1, out, NN, 1, 0);
    // layer 2
    k_gemm<<<gGemm, 256, 0, stream>>>(out, W2, hA);
    k_agg <<<gAgg, 256, 0, stream>>>(hA, rowp, col, dinv, b2, out, NN, 1, 0);
    // layer 3 (+ fused L2 normalize)
    k_gemm<<<gGemm, 256, 0, stream>>>(out, W3, hA);
    k_agg <<<gAgg, 256, 0, stream>>>(hA, rowp, col, dinv, b3, out, NN, 0, 1);
}

// Round 2
// 745.745 us; speedup vs baseline: 1.2225x; 1.2225x over previous
//
#include <hip/hip_runtime.h>
#include <cstdint>
#include <cstddef>

#define NN 100000
#define NE 1600000
#define D  128

// ---------------------------------------------------------------- CSR build
__global__ __launch_bounds__(256) void k_count(const int* __restrict__ dstv,
                                               int* __restrict__ cnt, int e4) {
    int i = blockIdx.x * 256 + threadIdx.x;
    if (i < e4) {
        int4 d = ((const int4*)dstv)[i];
        atomicAdd(&cnt[d.x], 1);
        atomicAdd(&cnt[d.y], 1);
        atomicAdd(&cnt[d.z], 1);
        atomicAdd(&cnt[d.w], 1);
    }
}

// chunk = 1024 elements per block (256 threads x 4); also emits dinv
__global__ __launch_bounds__(256) void k_scan1(const int* __restrict__ cnt,
                                               int* __restrict__ rowptr,
                                               int* __restrict__ bsum,
                                               float* __restrict__ dinv, int n) {
    __shared__ int s[256];
    int tid = threadIdx.x;
    int base = blockIdx.x * 1024 + tid * 4;
    int v[4]; int sum = 0;
#pragma unroll
    for (int j = 0; j < 4; ++j) {
        int idx = base + j;
        v[j] = (idx < n) ? cnt[idx] : 0;
        if (idx < n) dinv[idx] = rsqrtf((float)v[j] + 1.0f);
        sum += v[j];
    }
    s[tid] = sum;
    __syncthreads();
    for (int off = 1; off < 256; off <<= 1) {
        int t = (tid >= off) ? s[tid - off] : 0;
        __syncthreads();
        s[tid] += t;
        __syncthreads();
    }
    if (tid == 255) bsum[blockIdx.x] = s[255];
    int run = (tid > 0) ? s[tid - 1] : 0;
#pragma unroll
    for (int j = 0; j < 4; ++j) { int idx = base + j; if (idx < n) rowptr[idx] = run; run += v[j]; }
}

__global__ void k_scan2(const int* __restrict__ bsum, int* __restrict__ boff, int nb) {
    if (threadIdx.x == 0 && blockIdx.x == 0) {
        int run = 0;
        for (int i = 0; i < nb; ++i) { int t = bsum[i]; boff[i] = run; run += t; }
    }
}

__global__ __launch_bounds__(256) void k_add(int* __restrict__ rowptr,
                                             const int* __restrict__ boff,
                                             int* __restrict__ cursor, int n, int e) {
    int i = blockIdx.x * 256 + threadIdx.x;
    if (i < n) { int v = rowptr[i] + boff[i >> 10]; rowptr[i] = v; cursor[i] = v; }
    if (i == 0) rowptr[n] = e;
}

// packed edge record: {src, bits(dinv[src])}
__global__ __launch_bounds__(256) void k_fill(const int* __restrict__ srcv,
                                              const int* __restrict__ dstv,
                                              const float* __restrict__ dinv,
                                              int* __restrict__ cursor,
                                              int2* __restrict__ ed, int e) {
    int i = blockIdx.x * 256 + threadIdx.x;
    if (i < e) {
        int s = srcv[i];
        int d = dstv[i];
        float w = dinv[s];
        int p = atomicAdd(&cursor[d], 1);
        ed[p] = make_int2(s, __float_as_int(w));
    }
}

// ---------------------------------------------------------------- GEMM  Y = X @ W
// 32 rows x 128 cols per block, full W staged in LDS, 4x4 register blocking.
__global__ __launch_bounds__(256) void k_gemm(const float* __restrict__ X,
                                              const float* __restrict__ W,
                                              float* __restrict__ Y) {
    __shared__ float4 sW[128 * 32];  // W[128][128]
    __shared__ float4 sX[32 * 32];   // X tile [32][128]
    int tid  = threadIdx.x;
    int row0 = blockIdx.x * 32;

    const float4* W4 = (const float4*)W;
    for (int i = tid; i < 4096; i += 256) sW[i] = W4[i];
    const float4* X4 = (const float4*)(X + (size_t)row0 * D);
    for (int i = tid; i < 1024; i += 256) sX[i] = X4[i];
    __syncthreads();

    int tx = tid & 31;   // col group of 4
    int ty = tid >> 5;   // row group of 4
    float acc[4][4] = {};

#pragma unroll 4
    for (int k = 0; k < 128; k += 4) {
        float4 b0 = sW[(k + 0) * 32 + tx];
        float4 b1 = sW[(k + 1) * 32 + tx];
        float4 b2 = sW[(k + 2) * 32 + tx];
        float4 b3 = sW[(k + 3) * 32 + tx];
#pragma unroll
        for (int i = 0; i < 4; ++i) {
            float4 a = sX[(ty * 4 + i) * 32 + (k >> 2)];
            acc[i][0] = fmaf(a.x, b0.x, fmaf(a.y, b1.x, fmaf(a.z, b2.x, fmaf(a.w, b3.x, acc[i][0]))));
            acc[i][1] = fmaf(a.x, b0.y, fmaf(a.y, b1.y, fmaf(a.z, b2.y, fmaf(a.w, b3.y, acc[i][1]))));
            acc[i][2] = fmaf(a.x, b0.z, fmaf(a.y, b1.z, fmaf(a.z, b2.z, fmaf(a.w, b3.z, acc[i][2]))));
            acc[i][3] = fmaf(a.x, b0.w, fmaf(a.y, b1.w, fmaf(a.z, b2.w, fmaf(a.w, b3.w, acc[i][3]))));
        }
    }

#pragma unroll
    for (int i = 0; i < 4; ++i) {
        int r = row0 + ty * 4 + i;
        float4 o = make_float4(acc[i][0], acc[i][1], acc[i][2], acc[i][3]);
        *(float4*)&Y[(size_t)r * D + tx * 4] = o;
    }
}

// ---------------------------------------------------------------- aggregation
// one 64-lane wave per destination node, 2 floats per lane.
// 8-deep unrolled edge loop: 8 independent 512B gathers in flight per wave.
__global__ __launch_bounds__(256) void k_agg(const float* __restrict__ H,
                                             const int* __restrict__ rowptr,
                                             const int2* __restrict__ ed,
                                             const float* __restrict__ dinv,
                                             const float* __restrict__ bias,
                                             float* __restrict__ out,
                                             int relu, int normalize) {
    int node = blockIdx.x * 4 + (threadIdx.x >> 6);
    int lane = threadIdx.x & 63;
    if (node >= NN) return;

    const float2* __restrict__ H2 = (const float2*)H;
    float di  = dinv[node];
    int beg = rowptr[node];
    int end = rowptr[node + 1];

    float sx0=0.f,sy0=0.f,sx1=0.f,sy1=0.f,sx2=0.f,sy2=0.f,sx3=0.f,sy3=0.f;
    float sx4=0.f,sy4=0.f,sx5=0.f,sy5=0.f,sx6=0.f,sy6=0.f,sx7=0.f,sy7=0.f;

    int e = beg;
    for (; e + 8 <= end; e += 8) {
        int2 p0=ed[e],p1=ed[e+1],p2=ed[e+2],p3=ed[e+3];
        int2 p4=ed[e+4],p5=ed[e+5],p6=ed[e+6],p7=ed[e+7];
        float2 v0=H2[(p0.x<<6)+lane];
        float2 v1=H2[(p1.x<<6)+lane];
        float2 v2=H2[(p2.x<<6)+lane];
        float2 v3=H2[(p3.x<<6)+lane];
        float2 v4=H2[(p4.x<<6)+lane];
        float2 v5=H2[(p5.x<<6)+lane];
        float2 v6=H2[(p6.x<<6)+lane];
        float2 v7=H2[(p7.x<<6)+lane];
        sx0=fmaf(__int_as_float(p0.y),v0.x,sx0); sy0=fmaf(__int_as_float(p0.y),v0.y,sy0);
        sx1=fmaf(__int_as_float(p1.y),v1.x,sx1); sy1=fmaf(__int_as_float(p1.y),v1.y,sy1);
        sx2=fmaf(__int_as_float(p2.y),v2.x,sx2); sy2=fmaf(__int_as_float(p2.y),v2.y,sy2);
        sx3=fmaf(__int_as_float(p3.y),v3.x,sx3); sy3=fmaf(__int_as_float(p3.y),v3.y,sy3);
        sx4=fmaf(__int_as_float(p4.y),v4.x,sx4); sy4=fmaf(__int_as_float(p4.y),v4.y,sy4);
        sx5=fmaf(__int_as_float(p5.y),v5.x,sx5); sy5=fmaf(__int_as_float(p5.y),v5.y,sy5);
        sx6=fmaf(__int_as_float(p6.y),v6.x,sx6); sy6=fmaf(__int_as_float(p6.y),v6.y,sy6);
        sx7=fmaf(__int_as_float(p7.y),v7.x,sx7); sy7=fmaf(__int_as_float(p7.y),v7.y,sy7);
    }
    for (; e + 4 <= end; e += 4) {
        int2 p0=ed[e],p1=ed[e+1],p2=ed[e+2],p3=ed[e+3];
        float2 v0=H2[(p0.x<<6)+lane];
        float2 v1=H2[(p1.x<<6)+lane];
        float2 v2=H2[(p2.x<<6)+lane];
        float2 v3=H2[(p3.x<<6)+lane];
        sx0=fmaf(__int_as_float(p0.y),v0.x,sx0); sy0=fmaf(__int_as_float(p0.y),v0.y,sy0);
        sx1=fmaf(__int_as_float(p1.y),v1.x,sx1); sy1=fmaf(__int_as_float(p1.y),v1.y,sy1);
        sx2=fmaf(__int_as_float(p2.y),v2.x,sx2); sy2=fmaf(__int_as_float(p2.y),v2.y,sy2);
        sx3=fmaf(__int_as_float(p3.y),v3.x,sx3); sy3=fmaf(__int_as_float(p3.y),v3.y,sy3);
    }
    for (; e < end; ++e) {
        int2 p=ed[e];
        float2 v=H2[(p.x<<6)+lane];
        sx0=fmaf(__int_as_float(p.y),v.x,sx0); sy0=fmaf(__int_as_float(p.y),v.y,sy0);
    }
    float ax = ((sx0+sx4)+(sx1+sx5)) + ((sx2+sx6)+(sx3+sx7));
    float ay = ((sy0+sy4)+(sy1+sy5)) + ((sy2+sy6)+(sy3+sy7));

    float2 hv = H2[(node<<6)+lane];
    ax = fmaf(di, hv.x, ax);   // + dinv[v]*h[v]
    ay = fmaf(di, hv.y, ay);
    float2 bv = ((const float2*)bias)[lane];
    float ox = fmaf(di, ax, bv.x);
    float oy = fmaf(di, ay, bv.y);

    if (relu) {
        ox = fmaxf(ox, 0.0f);
        oy = fmaxf(oy, 0.0f);
    }
    if (normalize) {
        float ss = ox * ox + oy * oy;
#pragma unroll
        for (int off = 32; off > 0; off >>= 1) ss += __shfl_xor(ss, off, 64);
        float nrm = fmaxf(sqrtf(ss), 1e-12f);
        float inv = 1.0f / nrm;
        ox *= inv; oy *= inv;
    }
    float2* O2 = (float2*)out;
    float2 o; o.x = ox; o.y = oy;
    O2[(size_t)node * 64 + lane] = o;
}

// ---------------------------------------------------------------- launch
extern "C" void kernel_launch(void* const* d_in, const int* in_sizes, int n_in,
                              void* d_out, int out_size, void* d_ws, size_t ws_size,
                              hipStream_t stream) {
    const float* x  = (const float*)d_in[0];
    const int*   ei = (const int*)d_in[1];
    const float* W1 = (const float*)d_in[2];
    const float* b1 = (const float*)d_in[3];
    const float* W2 = (const float*)d_in[4];
    const float* b2 = (const float*)d_in[5];
    const float* W3 = (const float*)d_in[6];
    const float* b3 = (const float*)d_in[7];
    float* out = (float*)d_out;

    const int* srcv = ei;
    const int* dstv = ei + NE;

    // workspace carve
    char* w = (char*)d_ws;
    float* hA    = (float*)w; w += (size_t)NN * D * sizeof(float);   // 51.2 MB
    int*   degc  = (int*)w;   w += (size_t)NN * sizeof(int);
    float* dinv  = (float*)w; w += (size_t)NN * sizeof(float);
    int*   rowp  = (int*)w;   w += (size_t)(NN + 4) * sizeof(int);
    int*   curs  = (int*)w;   w += (size_t)NN * sizeof(int);
    int*   bsum  = (int*)w;   w += 128 * sizeof(int);
    int*   boff  = (int*)w;   w += 128 * sizeof(int);
    int2*  ed    = (int2*)w;  w += (size_t)NE * sizeof(int2);        // 12.8 MB

    const int nb = (NN + 1023) / 1024;  // 98

    hipMemsetAsync(degc, 0, (size_t)NN * sizeof(int), stream);
    k_count<<<(NE / 4 + 255) / 256, 256, 0, stream>>>(dstv, degc, NE / 4);
    k_scan1<<<nb, 256, 0, stream>>>(degc, rowp, bsum, dinv, NN);
    k_scan2<<<1, 64, 0, stream>>>(bsum, boff, nb);
    k_add  <<<(NN + 255) / 256, 256, 0, stream>>>(rowp, boff, curs, NN, NE);
    k_fill <<<(NE + 255) / 256, 256, 0, stream>>>(srcv, dstv, dinv, curs, ed, NE);

    dim3 gGemm(NN / 32);      // 100000 / 32 = 3125 exactly
    dim3 gAgg((NN + 3) / 4);  // 4 nodes per 256-thread block

    // layer 1
    k_gemm<<<gGemm, 256, 0, stream>>>(x, W1, hA);
    k_agg <<<gAgg, 256, 0, stream>>>(hA, rowp, ed, dinv, b1, out, 1, 0);
    // layer 2
    k_gemm<<<gGemm, 256, 0, stream>>>(out, W2, hA);
    k_agg <<<gAgg, 256, 0, stream>>>(hA, rowp, ed, dinv, b2, out, 1, 0);
    // layer 3 (+ fused L2 normalize)
    k_gemm<<<gGemm, 256, 0, stream>>>(out, W3, hA);
    k_agg <<<gAgg, 256, 0, stream>>>(hA, rowp, ed, dinv, b3, out, 0, 1);
}

// Round 3
// 581.390 us; speedup vs baseline: 1.5681x; 1.2827x over previous
//
#include <hip/hip_runtime.h>
#include <cstdint>
#include <cstddef>

#define NN 100000
#define NE 1600000
#define D  128

// bf16 helpers (manual, RNE)
__device__ __forceinline__ unsigned short f32_to_bf16(float f) {
    unsigned int b = __float_as_uint(f);
    unsigned int rounded = b + 0x7FFFu + ((b >> 16) & 1u);
    return (unsigned short)(rounded >> 16);
}
__device__ __forceinline__ float bf16_to_f32(unsigned short u) {
    return __uint_as_float(((unsigned int)u) << 16);
}

// ---------------------------------------------------------------- CSR build
__global__ __launch_bounds__(256) void k_count(const int* __restrict__ dstv,
                                               int* __restrict__ cnt, int e4) {
    int i = blockIdx.x * 256 + threadIdx.x;
    if (i < e4) {
        int4 d = ((const int4*)dstv)[i];
        atomicAdd(&cnt[d.x], 1);
        atomicAdd(&cnt[d.y], 1);
        atomicAdd(&cnt[d.z], 1);
        atomicAdd(&cnt[d.w], 1);
    }
}

// chunk = 1024 elements per block (256 threads x 4); also emits dinv
__global__ __launch_bounds__(256) void k_scan1(const int* __restrict__ cnt,
                                               int* __restrict__ rowptr,
                                               int* __restrict__ bsum,
                                               float* __restrict__ dinv, int n) {
    __shared__ int s[256];
    int tid = threadIdx.x;
    int base = blockIdx.x * 1024 + tid * 4;
    int v[4]; int sum = 0;
#pragma unroll
    for (int j = 0; j < 4; ++j) {
        int idx = base + j;
        v[j] = (idx < n) ? cnt[idx] : 0;
        if (idx < n) dinv[idx] = rsqrtf((float)v[j] + 1.0f);
        sum += v[j];
    }
    s[tid] = sum;
    __syncthreads();
    for (int off = 1; off < 256; off <<= 1) {
        int t = (tid >= off) ? s[tid - off] : 0;
        __syncthreads();
        s[tid] += t;
        __syncthreads();
    }
    if (tid == 255) bsum[blockIdx.x] = s[255];
    int run = (tid > 0) ? s[tid - 1] : 0;
#pragma unroll
    for (int j = 0; j < 4; ++j) { int idx = base + j; if (idx < n) rowptr[idx] = run; run += v[j]; }
}

__global__ void k_scan2(const int* __restrict__ bsum, int* __restrict__ boff, int nb) {
    if (threadIdx.x == 0 && blockIdx.x == 0) {
        int run = 0;
        for (int i = 0; i < nb; ++i) { int t = bsum[i]; boff[i] = run; run += t; }
    }
}

__global__ __launch_bounds__(256) void k_add(int* __restrict__ rowptr,
                                             const int* __restrict__ boff,
                                             int* __restrict__ cursor, int n, int e) {
    int i = blockIdx.x * 256 + threadIdx.x;
    if (i < n) { int v = rowptr[i] + boff[i >> 10]; rowptr[i] = v; cursor[i] = v; }
    if (i == 0) rowptr[n] = e;
}

// packed edge record: {src, bits(dinv[src])}
__global__ __launch_bounds__(256) void k_fill(const int* __restrict__ srcv,
                                              const int* __restrict__ dstv,
                                              const float* __restrict__ dinv,
                                              int* __restrict__ cursor,
                                              int2* __restrict__ ed, int e) {
    int i = blockIdx.x * 256 + threadIdx.x;
    if (i < e) {
        int s = srcv[i];
        int d = dstv[i];
        float w = dinv[s];
        int p = atomicAdd(&cursor[d], 1);
        ed[p] = make_int2(s, __float_as_int(w));
    }
}

// ---------------------------------------------------------------- GEMM  Yb = bf16(X @ W)
// 32 rows x 128 cols per block, full W staged in LDS, 4x4 register blocking.
__global__ __launch_bounds__(256) void k_gemm(const float* __restrict__ X,
                                              const float* __restrict__ W,
                                              unsigned short* __restrict__ Yb) {
    __shared__ float4 sW[128 * 32];  // W[128][128]
    __shared__ float4 sX[32 * 32];   // X tile [32][128]
    int tid  = threadIdx.x;
    int row0 = blockIdx.x * 32;

    const float4* W4 = (const float4*)W;
    for (int i = tid; i < 4096; i += 256) sW[i] = W4[i];
    const float4* X4 = (const float4*)(X + (size_t)row0 * D);
    for (int i = tid; i < 1024; i += 256) sX[i] = X4[i];
    __syncthreads();

    int tx = tid & 31;   // col group of 4
    int ty = tid >> 5;   // row group of 4
    float acc[4][4] = {};

#pragma unroll 4
    for (int k = 0; k < 128; k += 4) {
        float4 b0 = sW[(k + 0) * 32 + tx];
        float4 b1 = sW[(k + 1) * 32 + tx];
        float4 b2 = sW[(k + 2) * 32 + tx];
        float4 b3 = sW[(k + 3) * 32 + tx];
#pragma unroll
        for (int i = 0; i < 4; ++i) {
            float4 a = sX[(ty * 4 + i) * 32 + (k >> 2)];
            acc[i][0] = fmaf(a.x, b0.x, fmaf(a.y, b1.x, fmaf(a.z, b2.x, fmaf(a.w, b3.x, acc[i][0]))));
            acc[i][1] = fmaf(a.x, b0.y, fmaf(a.y, b1.y, fmaf(a.z, b2.y, fmaf(a.w, b3.y, acc[i][1]))));
            acc[i][2] = fmaf(a.x, b0.z, fmaf(a.y, b1.z, fmaf(a.z, b2.z, fmaf(a.w, b3.z, acc[i][2]))));
            acc[i][3] = fmaf(a.x, b0.w, fmaf(a.y, b1.w, fmaf(a.z, b2.w, fmaf(a.w, b3.w, acc[i][3]))));
        }
    }

#pragma unroll
    for (int i = 0; i < 4; ++i) {
        int r = row0 + ty * 4 + i;
        ushort4 o;
        o.x = f32_to_bf16(acc[i][0]);
        o.y = f32_to_bf16(acc[i][1]);
        o.z = f32_to_bf16(acc[i][2]);
        o.w = f32_to_bf16(acc[i][3]);
        *(ushort4*)&Yb[(size_t)r * D + tx * 4] = o;
    }
}

// ---------------------------------------------------------------- aggregation
// one 64-lane wave per destination node, 2 bf16 (4B) per lane.
// 8-deep unrolled edge loop: 8 independent 256B gathers in flight per wave.
__global__ __launch_bounds__(256) void k_agg(const unsigned short* __restrict__ Hb,
                                             const int* __restrict__ rowptr,
                                             const int2* __restrict__ ed,
                                             const float* __restrict__ dinv,
                                             const float* __restrict__ bias,
                                             float* __restrict__ out,
                                             int relu, int normalize) {
    int node = blockIdx.x * 4 + (threadIdx.x >> 6);
    int lane = threadIdx.x & 63;
    if (node >= NN) return;

    const ushort2* __restrict__ H2 = (const ushort2*)Hb;
    float di  = dinv[node];
    int beg = rowptr[node];
    int end = rowptr[node + 1];

    float sx0=0.f,sy0=0.f,sx1=0.f,sy1=0.f,sx2=0.f,sy2=0.f,sx3=0.f,sy3=0.f;
    float sx4=0.f,sy4=0.f,sx5=0.f,sy5=0.f,sx6=0.f,sy6=0.f,sx7=0.f,sy7=0.f;

    int e = beg;
    for (; e + 8 <= end; e += 8) {
        int2 p0=ed[e],p1=ed[e+1],p2=ed[e+2],p3=ed[e+3];
        int2 p4=ed[e+4],p5=ed[e+5],p6=ed[e+6],p7=ed[e+7];
        ushort2 r0=H2[(p0.x<<6)+lane];
        ushort2 r1=H2[(p1.x<<6)+lane];
        ushort2 r2=H2[(p2.x<<6)+lane];
        ushort2 r3=H2[(p3.x<<6)+lane];
        ushort2 r4=H2[(p4.x<<6)+lane];
        ushort2 r5=H2[(p5.x<<6)+lane];
        ushort2 r6=H2[(p6.x<<6)+lane];
        ushort2 r7=H2[(p7.x<<6)+lane];
        sx0=fmaf(__int_as_float(p0.y),bf16_to_f32(r0.x),sx0); sy0=fmaf(__int_as_float(p0.y),bf16_to_f32(r0.y),sy0);
        sx1=fmaf(__int_as_float(p1.y),bf16_to_f32(r1.x),sx1); sy1=fmaf(__int_as_float(p1.y),bf16_to_f32(r1.y),sy1);
        sx2=fmaf(__int_as_float(p2.y),bf16_to_f32(r2.x),sx2); sy2=fmaf(__int_as_float(p2.y),bf16_to_f32(r2.y),sy2);
        sx3=fmaf(__int_as_float(p3.y),bf16_to_f32(r3.x),sx3); sy3=fmaf(__int_as_float(p3.y),bf16_to_f32(r3.y),sy3);
        sx4=fmaf(__int_as_float(p4.y),bf16_to_f32(r4.x),sx4); sy4=fmaf(__int_as_float(p4.y),bf16_to_f32(r4.y),sy4);
        sx5=fmaf(__int_as_float(p5.y),bf16_to_f32(r5.x),sx5); sy5=fmaf(__int_as_float(p5.y),bf16_to_f32(r5.y),sy5);
        sx6=fmaf(__int_as_float(p6.y),bf16_to_f32(r6.x),sx6); sy6=fmaf(__int_as_float(p6.y),bf16_to_f32(r6.y),sy6);
        sx7=fmaf(__int_as_float(p7.y),bf16_to_f32(r7.x),sx7); sy7=fmaf(__int_as_float(p7.y),bf16_to_f32(r7.y),sy7);
    }
    for (; e + 4 <= end; e += 4) {
        int2 p0=ed[e],p1=ed[e+1],p2=ed[e+2],p3=ed[e+3];
        ushort2 r0=H2[(p0.x<<6)+lane];
        ushort2 r1=H2[(p1.x<<6)+lane];
        ushort2 r2=H2[(p2.x<<6)+lane];
        ushort2 r3=H2[(p3.x<<6)+lane];
        sx0=fmaf(__int_as_float(p0.y),bf16_to_f32(r0.x),sx0); sy0=fmaf(__int_as_float(p0.y),bf16_to_f32(r0.y),sy0);
        sx1=fmaf(__int_as_float(p1.y),bf16_to_f32(r1.x),sx1); sy1=fmaf(__int_as_float(p1.y),bf16_to_f32(r1.y),sy1);
        sx2=fmaf(__int_as_float(p2.y),bf16_to_f32(r2.x),sx2); sy2=fmaf(__int_as_float(p2.y),bf16_to_f32(r2.y),sy2);
        sx3=fmaf(__int_as_float(p3.y),bf16_to_f32(r3.x),sx3); sy3=fmaf(__int_as_float(p3.y),bf16_to_f32(r3.y),sy3);
    }
    for (; e < end; ++e) {
        int2 p=ed[e];
        ushort2 r=H2[(p.x<<6)+lane];
        sx0=fmaf(__int_as_float(p.y),bf16_to_f32(r.x),sx0); sy0=fmaf(__int_as_float(p.y),bf16_to_f32(r.y),sy0);
    }
    float ax = ((sx0+sx4)+(sx1+sx5)) + ((sx2+sx6)+(sx3+sx7));
    float ay = ((sy0+sy4)+(sy1+sy5)) + ((sy2+sy6)+(sy3+sy7));

    ushort2 hv = H2[(node<<6)+lane];
    ax = fmaf(di, bf16_to_f32(hv.x), ax);   // + dinv[v]*h[v]
    ay = fmaf(di, bf16_to_f32(hv.y), ay);
    float2 bv = ((const float2*)bias)[lane];
    float ox = fmaf(di, ax, bv.x);
    float oy = fmaf(di, ay, bv.y);

    if (relu) {
        ox = fmaxf(ox, 0.0f);
        oy = fmaxf(oy, 0.0f);
    }
    if (normalize) {
        float ss = ox * ox + oy * oy;
#pragma unroll
        for (int off = 32; off > 0; off >>= 1) ss += __shfl_xor(ss, off, 64);
        float nrm = fmaxf(sqrtf(ss), 1e-12f);
        float inv = 1.0f / nrm;
        ox *= inv; oy *= inv;
    }
    float2* O2 = (float2*)out;
    float2 o; o.x = ox; o.y = oy;
    O2[(size_t)node * 64 + lane] = o;
}

// ---------------------------------------------------------------- launch
extern "C" void kernel_launch(void* const* d_in, const int* in_sizes, int n_in,
                              void* d_out, int out_size, void* d_ws, size_t ws_size,
                              hipStream_t stream) {
    const float* x  = (const float*)d_in[0];
    const int*   ei = (const int*)d_in[1];
    const float* W1 = (const float*)d_in[2];
    const float* b1 = (const float*)d_in[3];
    const float* W2 = (const float*)d_in[4];
    const float* b2 = (const float*)d_in[5];
    const float* W3 = (const float*)d_in[6];
    const float* b3 = (const float*)d_in[7];
    float* out = (float*)d_out;

    const int* srcv = ei;
    const int* dstv = ei + NE;

    // workspace carve
    char* w = (char*)d_ws;
    unsigned short* hB = (unsigned short*)w; w += (size_t)NN * D * sizeof(unsigned short); // 25.6 MB
    int*   degc  = (int*)w;   w += (size_t)NN * sizeof(int);
    float* dinv  = (float*)w; w += (size_t)NN * sizeof(float);
    int*   rowp  = (int*)w;   w += (size_t)(NN + 4) * sizeof(int);
    int*   curs  = (int*)w;   w += (size_t)NN * sizeof(int);
    int*   bsum  = (int*)w;   w += 128 * sizeof(int);
    int*   boff  = (int*)w;   w += 128 * sizeof(int);
    int2*  ed    = (int2*)w;  w += (size_t)NE * sizeof(int2);        // 12.8 MB

    const int nb = (NN + 1023) / 1024;  // 98

    hipMemsetAsync(degc, 0, (size_t)NN * sizeof(int), stream);
    k_count<<<(NE / 4 + 255) / 256, 256, 0, stream>>>(dstv, degc, NE / 4);
    k_scan1<<<nb, 256, 0, stream>>>(degc, rowp, bsum, dinv, NN);
    k_scan2<<<1, 64, 0, stream>>>(bsum, boff, nb);
    k_add  <<<(NN + 255) / 256, 256, 0, stream>>>(rowp, boff, curs, NN, NE);
    k_fill <<<(NE + 255) / 256, 256, 0, stream>>>(srcv, dstv, dinv, curs, ed, NE);

    dim3 gGemm(NN / 32);      // 100000 / 32 = 3125 exactly
    dim3 gAgg((NN + 3) / 4);  // 4 nodes per 256-thread block

    // layer 1
    k_gemm<<<gGemm, 256, 0, stream>>>(x, W1, hB);
    k_agg <<<gAgg, 256, 0, stream>>>(hB, rowp, ed, dinv, b1, out, 1, 0);
    // layer 2
    k_gemm<<<gGemm, 256, 0, stream>>>(out, W2, hB);
    k_agg <<<gAgg, 256, 0, stream>>>(hB, rowp, ed, dinv, b2, out, 1, 0);
    // layer 3 (+ fused L2 normalize)
    k_gemm<<<gGemm, 256, 0, stream>>>(out, W3, hB);
    k_agg <<<gAgg, 256, 0, stream>>>(hB, rowp, ed, dinv, b3, out, 0, 1);
}